// Round 14
// baseline (46.081 us; speedup 1.0000x reference)
//
#include <hip/hip_runtime.h>
#include <hip/hip_bf16.h>
#include <math.h>
#include <stdint.h>

// DynamicViewSampler — prep (m -> fragment bf16 + per-tile den) +
// GEMM (bf16 MFMA, A from ws, B staged LDS, 1-deep prefetch = R8 structure) +
// reduce (per-(b,v) block, den from den_tile).
// Round-14 delta: KCH 8 -> 4. Gemm is BW-bound (R11/R13 pipeline-depth nulls);
// halving the f32 partial round-trip (33+32 MB -> 17+17 MB) is the remaining
// byte lever. 512 blocks = 2/CU still saturates BW (in-flight >> BW*latency).

constexpr int VV  = 64;    // views (M)
constexpr int DC  = 128;   // D cols per block (N)
constexpr int KS  = 64;    // L rows per tile
constexpr int NTH = 256;
constexpr int ST2 = 134;   // smB row stride in bf16 units (conflict-free gather)
constexpr int KCH = 4;     // chunks per batch

typedef __attribute__((ext_vector_type(8))) short short8;
typedef __attribute__((ext_vector_type(4))) float f32x4;

static __device__ __forceinline__ unsigned short f2bf(float f) {
    __hip_bfloat16 h = __float2bfloat16(f);
    return __builtin_bit_cast(unsigned short, h);
}

// ---------------- prep: m tiles (fragment order) + per-tile den ----------------
__global__ __launch_bounds__(256)
void dvs_prep(const int* __restrict__ v_len, const int* __restrict__ gthw,
              const float* __restrict__ centers,
              unsigned short* __restrict__ mws,     // [B][NT][8][64] short8
              float* __restrict__ den_tile,         // [B][NT][64]
              int NT)
{
    const int t = blockIdx.x, b = blockIdx.y;
    const int Lv = v_len[b];
    const int lt = t * KS;
    if (lt >= Lv) return;

    const float Hf = (float)gthw[b*3 + 1];
    const float Wf = (float)gthw[b*3 + 2];
    const float sq = sqrtf((float)Lv * (Wf / Hf));
    int W_eff = (int)rintf(sq);                       if (W_eff < 1) W_eff = 1;
    int H_eff = (int)ceilf((float)Lv / (float)W_eff); if (H_eff < 1) H_eff = 1;
    const float invW = 1.f / (float)W_eff, invH = 1.f / (float)H_eff;

    const int tid  = threadIdx.x;
    const int lane = tid & 63, wave = tid >> 6;
    const int ar = lane & 15, koct = lane >> 4;

    __shared__ float sden[2][4][VV];

    short8* mtile = (short8*)mws + ((size_t)b * NT + t) * 8 * 64;

#pragma unroll
    for (int i = 0; i < 2; ++i) {
        const int f  = wave * 2 + i;
        const int ks = f >> 2, mf = f & 3;
        const int v  = mf * 16 + ar;
        const float2 ctr = ((const float2*)centers)[(size_t)b * VV + v];

        int l   = lt + ks * 32 + koct * 8;
        int row = l / W_eff;
        int col = l - row * W_eff;
        float y = (float)row * invH;

        union { unsigned short h[8]; short8 s; } ap;
        float ds = 0.f;
#pragma unroll
        for (int j = 0; j < 8; ++j) {
            float m = 0.f;
            if (l + j < Lv) {
                const float x  = (float)col * invW;
                const float dx = ctr.x - x, dy = ctr.y - y;
                m = __expf(-20.f * (dx * dx + dy * dy));
            }
            ds += m;
            ap.h[j] = f2bf(m);
            if (++col == W_eff) { col = 0; ++row; y = (float)row * invH; }
        }
        mtile[f * 64 + lane] = ap.s;
        sden[ks][koct][v] = ds;           // unique (ks,koct,v) per (f,lane)
    }
    __syncthreads();
    if (tid < VV) {
        float s = 0.f;
#pragma unroll
        for (int ks = 0; ks < 2; ++ks)
#pragma unroll
            for (int q = 0; q < 4; ++q) s += sden[ks][q][tid];
        den_tile[((size_t)b * NT + t) * VV + tid] = s;
    }
}

// -------- GEMM: A from ws (global b128), B staged LDS, 1-deep prefetch --------
__global__ __launch_bounds__(NTH)
void dvs_mfma(const float* __restrict__ v_pad, const int* __restrict__ v_len,
              const unsigned short* __restrict__ mws,
              float* __restrict__ num_part,   // [B][KCH][V][D] f32
              int L, int D, int NT)
{
    const int kblk = blockIdx.x, dcb = blockIdx.y, b = blockIdx.z;
    const int Lv = v_len[b];
    const int chunk = (((Lv + KCH - 1) / KCH) + 63) & ~63;   // 64-aligned
    const int l0 = kblk * chunk;
    if (l0 >= Lv) return;
    const int l1 = min(l0 + chunk, Lv);

    const int tid  = threadIdx.x;
    const int d0   = dcb * DC;
    const int lane = tid & 63;
    const int wave = tid >> 6;

    __shared__ __align__(16) unsigned short smB[KS][ST2];   // ~16.75 KB

    const int sd   = tid & 31;    // B-staging: 32 float4 cols
    const int srow = tid >> 5;    //            8 row-groups
    const int fcol = lane & 15, foct = lane >> 4;

    f32x4 acc[4][2];
#pragma unroll
    for (int i = 0; i < 4; ++i) {
        acc[i][0] = f32x4{0.f, 0.f, 0.f, 0.f};
        acc[i][1] = f32x4{0.f, 0.f, 0.f, 0.f};
    }

    const float*  vp_b  = v_pad + (size_t)b * L * D + d0;
    const short8* mws_b = (const short8*)mws + (size_t)b * NT * 8 * 64;

    // prologue: issue tile-0 B loads
    float4 ld[8];
#pragma unroll
    for (int it = 0; it < 8; ++it) {
        const int l = l0 + it * 8 + srow;
        ld[it] = make_float4(0.f, 0.f, 0.f, 0.f);
        if (l < l1)
            ld[it] = *(const float4*)(vp_b + (size_t)l * D + sd * 4);
    }

    for (int lt = l0; lt < l1; lt += KS) {
        // ---- stage B (regs from last iteration / prologue) ----
#pragma unroll
        for (int it = 0; it < 8; ++it) {
            const int lrow = it * 8 + srow;
            unsigned* w = (unsigned*)&smB[lrow][sd * 4];
            w[0] = (unsigned)f2bf(ld[it].x) | ((unsigned)f2bf(ld[it].y) << 16);
            w[1] = (unsigned)f2bf(ld[it].z) | ((unsigned)f2bf(ld[it].w) << 16);
        }
        __syncthreads();                       // tile staged

        // ---- prefetch next tile's B globals (fly under MFMA phase) ----
        const int ltn = lt + KS;
        if (ltn < l1) {
#pragma unroll
            for (int it = 0; it < 8; ++it) {
                const int l = ltn + it * 8 + srow;
                ld[it] = make_float4(0.f, 0.f, 0.f, 0.f);
                if (l < l1)
                    ld[it] = *(const float4*)(vp_b + (size_t)l * D + sd * 4);
            }
        }

        // ---- A fragments: direct coalesced b128 loads from ws (L2/L3) ----
        const short8* mt = mws_b + ((size_t)(lt >> 6)) * 8 * 64;
        short8 af[2][4];
#pragma unroll
        for (int ks = 0; ks < 2; ++ks)
#pragma unroll
            for (int mf = 0; mf < 4; ++mf)
                af[ks][mf] = mt[(ks * 4 + mf) * 64 + lane];

        // ---- MFMA: 2 k-halves x 4 m-frags x 2 n-frags ----
#pragma unroll
        for (int ks = 0; ks < 2; ++ks) {
#pragma unroll
            for (int nf = 0; nf < 2; ++nf) {
                const int colx  = wave * 32 + nf * 16 + fcol;
                const int kbase = ks * 32 + foct * 8;
                union { unsigned short h[8]; short8 s; } bf;
#pragma unroll
                for (int j = 0; j < 8; ++j)
                    bf.h[j] = smB[kbase + j][colx];
#pragma unroll
                for (int mf = 0; mf < 4; ++mf)
                    acc[mf][nf] = __builtin_amdgcn_mfma_f32_16x16x32_bf16(
                        af[ks][mf], bf.s, acc[mf][nf], 0, 0, 0);
            }
        }
        __syncthreads();                       // MFMA reads done; smB reusable
    }

    // ---- numerator partials (C/D: col=lane&15, row=(lane>>4)*4+r) ----
    float* basep = num_part + ((size_t)b * KCH + kblk) * VV * (size_t)D + d0 + wave * 32;
#pragma unroll
    for (int mf = 0; mf < 4; ++mf) {
#pragma unroll
        for (int nf = 0; nf < 2; ++nf) {
            const int colx = nf * 16 + fcol;
            const int row0 = mf * 16 + foct * 4;
#pragma unroll
            for (int r = 0; r < 4; ++r)
                basep[(size_t)(row0 + r) * D + colx] = acc[mf][nf][r];
        }
    }
}

// ---------------- reduce: one block per (b,v); den from den_tile ----------------
__global__ __launch_bounds__(256)
void dvs_reduce(const float* __restrict__ num_part,
                const float* __restrict__ den_tile,
                const int*   __restrict__ v_len,
                float*       __restrict__ out,
                int D, int NT)
{
    const int bv = blockIdx.x;
    const int b  = bv >> 6;
    const int v  = bv & 63;
    const int tid = threadIdx.x;              // d4 index (D/4 = 256)

    const int Lv    = v_len[b];
    const int chunk = (((Lv + KCH - 1) / KCH) + 63) & ~63;
    const int nk    = (Lv + chunk - 1) / chunk;
    const int nt    = (Lv + KS - 1) / KS;

    __shared__ float s64[64];
    __shared__ float sinv;
    if (tid < 64) {
        float s = 0.f;
        for (int t = tid; t < nt; t += 64)
            s += den_tile[((size_t)b * NT + t) * VV + v];
        s64[tid] = s;
    }
    __syncthreads();
    if (tid == 0) {
        float s = 1e-6f;
#pragma unroll
        for (int i = 0; i < 64; ++i) s += s64[i];
        sinv = 1.0f / s;
    }
    __syncthreads();

    float4 num = make_float4(0.f, 0.f, 0.f, 0.f);
    const float* np = num_part + ((size_t)b * KCH * VV + v) * (size_t)D + tid * 4;
    for (int k = 0; k < nk; ++k) {
        const float4 p = *(const float4*)(np + (size_t)k * VV * D);
        num.x += p.x; num.y += p.y; num.z += p.z; num.w += p.w;
    }
    const float inv = sinv;
    *(float4*)(out + (size_t)bv * D + tid * 4) =
        make_float4(num.x * inv, num.y * inv, num.z * inv, num.w * inv);
}

extern "C" void kernel_launch(void* const* d_in, const int* in_sizes, int n_in,
                              void* d_out, int out_size, void* d_ws, size_t ws_size,
                              hipStream_t stream)
{
    const float* v_pad     = (const float*)d_in[0];
    const int*   v_len     = (const int*)d_in[1];
    const int*   grid_thws = (const int*)d_in[2];
    const float* centers   = (const float*)d_in[3];
    float*       out       = (float*)d_out;

    const int B  = in_sizes[1];
    const int D  = out_size / (B * VV);
    const int L  = in_sizes[0] / (B * D);
    const int NT = (L + KS - 1) / KS;

    // workspace layout (all 16B-aligned)
    float*          num_part = (float*)d_ws;                               // B*KCH*V*D f32
    float*          den_tile = num_part + (size_t)B * KCH * VV * D;        // B*NT*V
    unsigned short* mws      = (unsigned short*)(den_tile + (size_t)B * NT * VV);

    dim3 gridP(NT, B);
    dvs_prep<<<gridP, 256, 0, stream>>>(v_len, grid_thws, centers, mws,
                                        den_tile, NT);

    dim3 gridG(KCH, D / DC, B);
    dvs_mfma<<<gridG, NTH, 0, stream>>>(v_pad, v_len, mws, num_part, L, D, NT);

    dvs_reduce<<<B * VV, 256, 0, stream>>>(num_part, den_tile, v_len, out, D, NT);
}

// Round 15
// 44.436 us; speedup vs baseline: 1.0370x; 1.0370x over previous
//
#include <hip/hip_runtime.h>
#include <hip/hip_bf16.h>
#include <math.h>
#include <stdint.h>

// DynamicViewSampler — prep (m -> fragment bf16 + per-tile den) +
// GEMM (bf16 MFMA, A from ws, B staged LDS, 1-deep prefetch) + reduce.
// EXACT round-8 structure (best, 42.8us); single change: XCD swizzle that
// co-locates the 8 dcb-blocks of one (b,kblk) on one XCD -> shared A-tile
// (mws) reads hit that XCD's L2 (8x amortization), v_pad rows stream once.
// flat = dcb*128 + b*8 + kblk  ->  XCD(flat%8) = kblk for all dcb sharers.

constexpr int VV  = 64;    // views (M)
constexpr int DC  = 128;   // D cols per block (N)
constexpr int KS  = 64;    // L rows per tile
constexpr int NTH = 256;
constexpr int ST2 = 134;   // smB row stride in bf16 units (conflict-free gather)
constexpr int KCH = 8;     // chunks per batch

typedef __attribute__((ext_vector_type(8))) short short8;
typedef __attribute__((ext_vector_type(4))) float f32x4;

static __device__ __forceinline__ unsigned short f2bf(float f) {
    __hip_bfloat16 h = __float2bfloat16(f);
    return __builtin_bit_cast(unsigned short, h);
}

// ---------------- prep: m tiles (fragment order) + per-tile den ----------------
__global__ __launch_bounds__(256)
void dvs_prep(const int* __restrict__ v_len, const int* __restrict__ gthw,
              const float* __restrict__ centers,
              unsigned short* __restrict__ mws,     // [B][NT][8][64] short8
              float* __restrict__ den_tile,         // [B][NT][64]
              int NT)
{
    const int t = blockIdx.x, b = blockIdx.y;
    const int Lv = v_len[b];
    const int lt = t * KS;
    if (lt >= Lv) return;

    const float Hf = (float)gthw[b*3 + 1];
    const float Wf = (float)gthw[b*3 + 2];
    const float sq = sqrtf((float)Lv * (Wf / Hf));
    int W_eff = (int)rintf(sq);                       if (W_eff < 1) W_eff = 1;
    int H_eff = (int)ceilf((float)Lv / (float)W_eff); if (H_eff < 1) H_eff = 1;
    const float invW = 1.f / (float)W_eff, invH = 1.f / (float)H_eff;

    const int tid  = threadIdx.x;
    const int lane = tid & 63, wave = tid >> 6;
    const int ar = lane & 15, koct = lane >> 4;

    __shared__ float sden[2][4][VV];

    short8* mtile = (short8*)mws + ((size_t)b * NT + t) * 8 * 64;

#pragma unroll
    for (int i = 0; i < 2; ++i) {
        const int f  = wave * 2 + i;
        const int ks = f >> 2, mf = f & 3;
        const int v  = mf * 16 + ar;
        const float2 ctr = ((const float2*)centers)[(size_t)b * VV + v];

        int l   = lt + ks * 32 + koct * 8;
        int row = l / W_eff;
        int col = l - row * W_eff;
        float y = (float)row * invH;

        union { unsigned short h[8]; short8 s; } ap;
        float ds = 0.f;
#pragma unroll
        for (int j = 0; j < 8; ++j) {
            float m = 0.f;
            if (l + j < Lv) {
                const float x  = (float)col * invW;
                const float dx = ctr.x - x, dy = ctr.y - y;
                m = __expf(-20.f * (dx * dx + dy * dy));
            }
            ds += m;
            ap.h[j] = f2bf(m);
            if (++col == W_eff) { col = 0; ++row; y = (float)row * invH; }
        }
        mtile[f * 64 + lane] = ap.s;
        sden[ks][koct][v] = ds;           // unique (ks,koct,v) per (f,lane)
    }
    __syncthreads();
    if (tid < VV) {
        float s = 0.f;
#pragma unroll
        for (int ks = 0; ks < 2; ++ks)
#pragma unroll
            for (int q = 0; q < 4; ++q) s += sden[ks][q][tid];
        den_tile[((size_t)b * NT + t) * VV + tid] = s;
    }
}

// -------- GEMM: A from ws (global b128), B staged LDS, 1-deep prefetch --------
__global__ __launch_bounds__(NTH)
void dvs_mfma(const float* __restrict__ v_pad, const int* __restrict__ v_len,
              const unsigned short* __restrict__ mws,
              const float* __restrict__ den_tile,
              float* __restrict__ num_part,   // [B][KCH][V][D] f32
              float* __restrict__ den_part,   // [B][KCH][V]
              int L, int D, int NT)
{
    // XCD swizzle: flat = dcb*128 + b*8 + kblk
    //   -> all 8 dcb-sharers of (b,kblk) land on XCD (kblk % 8): A-tiles L2-hit.
    const int flat = blockIdx.x;
    const int dcb  = flat >> 7;
    const int g    = flat & 127;
    const int b    = g >> 3;
    const int kblk = g & 7;

    const int Lv = v_len[b];
    const int chunk = (((Lv + KCH - 1) / KCH) + 63) & ~63;   // 64-aligned
    const int l0 = kblk * chunk;
    if (l0 >= Lv) return;
    const int l1 = min(l0 + chunk, Lv);

    const int tid  = threadIdx.x;
    const int d0   = dcb * DC;
    const int lane = tid & 63;
    const int wave = tid >> 6;

    __shared__ __align__(16) unsigned short smB[KS][ST2];   // ~16.75 KB

    const int sd   = tid & 31;    // B-staging: 32 float4 cols
    const int srow = tid >> 5;    //            8 row-groups
    const int fcol = lane & 15, foct = lane >> 4;

    f32x4 acc[4][2];
#pragma unroll
    for (int i = 0; i < 4; ++i) {
        acc[i][0] = f32x4{0.f, 0.f, 0.f, 0.f};
        acc[i][1] = f32x4{0.f, 0.f, 0.f, 0.f};
    }
    float denacc = 0.f;

    const float*  vp_b  = v_pad + (size_t)b * L * D + d0;
    const short8* mws_b = (const short8*)mws + (size_t)b * NT * 8 * 64;
    const float*  dt_b  = den_tile + (size_t)b * NT * VV;

    // prologue: issue tile-0 B loads
    float4 ld[8];
#pragma unroll
    for (int it = 0; it < 8; ++it) {
        const int l = l0 + it * 8 + srow;
        ld[it] = make_float4(0.f, 0.f, 0.f, 0.f);
        if (l < l1)
            ld[it] = *(const float4*)(vp_b + (size_t)l * D + sd * 4);
    }

    for (int lt = l0; lt < l1; lt += KS) {
        // ---- stage B (regs from last iteration / prologue) ----
#pragma unroll
        for (int it = 0; it < 8; ++it) {
            const int lrow = it * 8 + srow;
            unsigned* w = (unsigned*)&smB[lrow][sd * 4];
            w[0] = (unsigned)f2bf(ld[it].x) | ((unsigned)f2bf(ld[it].y) << 16);
            w[1] = (unsigned)f2bf(ld[it].z) | ((unsigned)f2bf(ld[it].w) << 16);
        }
        __syncthreads();                       // tile staged

        // ---- prefetch next tile's B globals (fly under MFMA phase) ----
        const int ltn = lt + KS;
        if (ltn < l1) {
#pragma unroll
            for (int it = 0; it < 8; ++it) {
                const int l = ltn + it * 8 + srow;
                ld[it] = make_float4(0.f, 0.f, 0.f, 0.f);
                if (l < l1)
                    ld[it] = *(const float4*)(vp_b + (size_t)l * D + sd * 4);
            }
        }

        // ---- A fragments: direct coalesced b128 loads from ws (L2-shared) ----
        const short8* mt = mws_b + ((size_t)(lt >> 6)) * 8 * 64;
        short8 af[2][4];
#pragma unroll
        for (int ks = 0; ks < 2; ++ks)
#pragma unroll
            for (int mf = 0; mf < 4; ++mf)
                af[ks][mf] = mt[(ks * 4 + mf) * 64 + lane];

        // ---- den accumulate (one load per tile, dcb==0 only) ----
        if (dcb == 0 && tid < VV)
            denacc += dt_b[(size_t)(lt >> 6) * VV + tid];

        // ---- MFMA: 2 k-halves x 4 m-frags x 2 n-frags ----
#pragma unroll
        for (int ks = 0; ks < 2; ++ks) {
#pragma unroll
            for (int nf = 0; nf < 2; ++nf) {
                const int colx  = wave * 32 + nf * 16 + fcol;
                const int kbase = ks * 32 + foct * 8;
                union { unsigned short h[8]; short8 s; } bf;
#pragma unroll
                for (int j = 0; j < 8; ++j)
                    bf.h[j] = smB[kbase + j][colx];
#pragma unroll
                for (int mf = 0; mf < 4; ++mf)
                    acc[mf][nf] = __builtin_amdgcn_mfma_f32_16x16x32_bf16(
                        af[ks][mf], bf.s, acc[mf][nf], 0, 0, 0);
            }
        }
        __syncthreads();                       // MFMA reads done; smB reusable
    }

    // ---- den partial ----
    if (dcb == 0 && tid < VV)
        den_part[((size_t)b * KCH + kblk) * VV + tid] = denacc;

    // ---- numerator partials (C/D: col=lane&15, row=(lane>>4)*4+r) ----
    float* basep = num_part + ((size_t)b * KCH + kblk) * VV * (size_t)D + d0 + wave * 32;
#pragma unroll
    for (int mf = 0; mf < 4; ++mf) {
#pragma unroll
        for (int nf = 0; nf < 2; ++nf) {
            const int colx = nf * 16 + fcol;
            const int row0 = mf * 16 + foct * 4;
#pragma unroll
            for (int r = 0; r < 4; ++r)
                basep[(size_t)(row0 + r) * D + colx] = acc[mf][nf][r];
        }
    }
}

// ---------------- reduce ----------------
__global__ __launch_bounds__(256)
void dvs_reduce(const float* __restrict__ num_part,
                const float* __restrict__ den_part,
                const int*   __restrict__ v_len,
                float*       __restrict__ out,
                int D, int total4)
{
    const int idx = blockIdx.x * 256 + threadIdx.x;
    if (idx >= total4) return;
    const int dq4 = D / 4;
    const int d4  = idx % dq4;
    const int bv  = idx / dq4;
    const int b   = bv / VV;
    const int v   = bv - b * VV;

    const int Lv    = v_len[b];
    const int chunk = (((Lv + KCH - 1) / KCH) + 63) & ~63;
    const int nk    = (Lv + chunk - 1) / chunk;      // valid chunk slots

    float  den = 1e-6f;
    float4 num = make_float4(0.f, 0.f, 0.f, 0.f);
    for (int k = 0; k < nk; ++k) {
        den += den_part[((size_t)b * KCH + k) * VV + v];
        const float4 p = ((const float4*)(num_part +
                          (((size_t)b * KCH + k) * VV + v) * (size_t)D))[d4];
        num.x += p.x; num.y += p.y; num.z += p.z; num.w += p.w;
    }
    const float inv = 1.0f / den;
    ((float4*)out)[(size_t)bv * dq4 + d4] =
        make_float4(num.x * inv, num.y * inv, num.z * inv, num.w * inv);
}

extern "C" void kernel_launch(void* const* d_in, const int* in_sizes, int n_in,
                              void* d_out, int out_size, void* d_ws, size_t ws_size,
                              hipStream_t stream)
{
    const float* v_pad     = (const float*)d_in[0];
    const int*   v_len     = (const int*)d_in[1];
    const int*   grid_thws = (const int*)d_in[2];
    const float* centers   = (const float*)d_in[3];
    float*       out       = (float*)d_out;

    const int B  = in_sizes[1];
    const int D  = out_size / (B * VV);
    const int L  = in_sizes[0] / (B * D);
    const int NT = (L + KS - 1) / KS;

    // workspace layout (all 16B-aligned)
    float*          num_part = (float*)d_ws;                               // B*KCH*V*D f32
    float*          den_part = num_part + (size_t)B * KCH * VV * D;        // B*KCH*V
    float*          den_tile = den_part + (size_t)B * KCH * VV;            // B*NT*V
    unsigned short* mws      = (unsigned short*)(den_tile + (size_t)B * NT * VV);

    dim3 gridP(NT, B);
    dvs_prep<<<gridP, 256, 0, stream>>>(v_len, grid_thws, centers, mws,
                                        den_tile, NT);

    const int nblkG = (D / DC) * B * KCH;     // 1024, swizzled decode
    dvs_mfma<<<nblkG, NTH, 0, stream>>>(v_pad, v_len, mws, den_tile,
                                        num_part, den_part, L, D, NT);

    const int total4 = B * VV * D / 4;
    dvs_reduce<<<(total4 + 255) / 256, 256, 0, stream>>>(num_part, den_part,
                                                         v_len, out, D, total4);
}

// Round 16
// 42.272 us; speedup vs baseline: 1.0901x; 1.0512x over previous
//
#include <hip/hip_runtime.h>
#include <hip/hip_bf16.h>
#include <math.h>
#include <stdint.h>

// DynamicViewSampler — FINAL (round-8 optimum, 42.8us reproduced).
// 3-kernel: prep (m -> fragment-ordered bf16 tiles + per-tile den),
// GEMM (bf16 MFMA 16x16x32, A direct from ws, B staged LDS w/ 1-deep
// register prefetch, KCH=8 x DC=128 x B grid = 1024 blocks ~ 4/CU), reduce.
// Blended memory-system bound: ~280 MB moved / 42.8us ~ 6.5 TB/s (>= 6.3
// achievable HBM). Closed levers (all regressed): DC 64/256, CHUNK 256,
// KCH 4, f16 partials, split-K finisher (XCD fence serializes), LDS dbuf,
// 2-deep prefetch, XCD swizzles on either axis.

constexpr int VV  = 64;    // views (M)
constexpr int DC  = 128;   // D cols per block (N)
constexpr int KS  = 64;    // L rows per tile
constexpr int NTH = 256;
constexpr int ST2 = 134;   // smB row stride in bf16 units (conflict-free gather)
constexpr int KCH = 8;     // chunks per batch

typedef __attribute__((ext_vector_type(8))) short short8;
typedef __attribute__((ext_vector_type(4))) float f32x4;

static __device__ __forceinline__ unsigned short f2bf(float f) {
    __hip_bfloat16 h = __float2bfloat16(f);
    return __builtin_bit_cast(unsigned short, h);
}

// ---------------- prep: m tiles (fragment order) + per-tile den ----------------
__global__ __launch_bounds__(256)
void dvs_prep(const int* __restrict__ v_len, const int* __restrict__ gthw,
              const float* __restrict__ centers,
              unsigned short* __restrict__ mws,     // [B][NT][8][64] short8
              float* __restrict__ den_tile,         // [B][NT][64]
              int NT)
{
    const int t = blockIdx.x, b = blockIdx.y;
    const int Lv = v_len[b];
    const int lt = t * KS;
    if (lt >= Lv) return;

    const float Hf = (float)gthw[b*3 + 1];
    const float Wf = (float)gthw[b*3 + 2];
    const float sq = sqrtf((float)Lv * (Wf / Hf));
    int W_eff = (int)rintf(sq);                       if (W_eff < 1) W_eff = 1;
    int H_eff = (int)ceilf((float)Lv / (float)W_eff); if (H_eff < 1) H_eff = 1;
    const float invW = 1.f / (float)W_eff, invH = 1.f / (float)H_eff;

    const int tid  = threadIdx.x;
    const int lane = tid & 63, wave = tid >> 6;
    const int ar = lane & 15, koct = lane >> 4;

    __shared__ float sden[2][4][VV];

    short8* mtile = (short8*)mws + ((size_t)b * NT + t) * 8 * 64;

#pragma unroll
    for (int i = 0; i < 2; ++i) {
        const int f  = wave * 2 + i;
        const int ks = f >> 2, mf = f & 3;
        const int v  = mf * 16 + ar;
        const float2 ctr = ((const float2*)centers)[(size_t)b * VV + v];

        int l   = lt + ks * 32 + koct * 8;
        int row = l / W_eff;
        int col = l - row * W_eff;
        float y = (float)row * invH;

        union { unsigned short h[8]; short8 s; } ap;
        float ds = 0.f;
#pragma unroll
        for (int j = 0; j < 8; ++j) {
            float m = 0.f;
            if (l + j < Lv) {
                const float x  = (float)col * invW;
                const float dx = ctr.x - x, dy = ctr.y - y;
                m = __expf(-20.f * (dx * dx + dy * dy));
            }
            ds += m;
            ap.h[j] = f2bf(m);
            if (++col == W_eff) { col = 0; ++row; y = (float)row * invH; }
        }
        mtile[f * 64 + lane] = ap.s;
        sden[ks][koct][v] = ds;           // unique (ks,koct,v) per (f,lane)
    }
    __syncthreads();
    if (tid < VV) {
        float s = 0.f;
#pragma unroll
        for (int ks = 0; ks < 2; ++ks)
#pragma unroll
            for (int q = 0; q < 4; ++q) s += sden[ks][q][tid];
        den_tile[((size_t)b * NT + t) * VV + tid] = s;
    }
}

// ---------------- GEMM: A from ws (global b128), B staged in LDS ----------------
__global__ __launch_bounds__(NTH)
void dvs_mfma(const float* __restrict__ v_pad, const int* __restrict__ v_len,
              const unsigned short* __restrict__ mws,
              const float* __restrict__ den_tile,
              float* __restrict__ num_part,   // [B][KCH][V][D] f32
              float* __restrict__ den_part,   // [B][KCH][V]
              int L, int D, int NT)
{
    const int kblk = blockIdx.x, dcb = blockIdx.y, b = blockIdx.z;
    const int Lv = v_len[b];
    const int chunk = (((Lv + KCH - 1) / KCH) + 63) & ~63;   // 64-aligned
    const int l0 = kblk * chunk;
    if (l0 >= Lv) return;
    const int l1 = min(l0 + chunk, Lv);

    const int tid  = threadIdx.x;
    const int d0   = dcb * DC;
    const int lane = tid & 63;
    const int wave = tid >> 6;

    __shared__ __align__(16) unsigned short smB[KS][ST2];   // ~16.75 KB

    const int sd   = tid & 31;    // B-staging: 32 float4 cols
    const int srow = tid >> 5;    //            8 row-groups
    const int fcol = lane & 15, foct = lane >> 4;

    f32x4 acc[4][2];
#pragma unroll
    for (int i = 0; i < 4; ++i) {
        acc[i][0] = f32x4{0.f, 0.f, 0.f, 0.f};
        acc[i][1] = f32x4{0.f, 0.f, 0.f, 0.f};
    }
    float denacc = 0.f;

    const float*  vp_b  = v_pad + (size_t)b * L * D + d0;
    const short8* mws_b = (const short8*)mws + (size_t)b * NT * 8 * 64;
    const float*  dt_b  = den_tile + (size_t)b * NT * VV;

    // prologue: issue tile-0 B loads
    float4 ld[8];
#pragma unroll
    for (int it = 0; it < 8; ++it) {
        const int l = l0 + it * 8 + srow;
        ld[it] = make_float4(0.f, 0.f, 0.f, 0.f);
        if (l < l1)
            ld[it] = *(const float4*)(vp_b + (size_t)l * D + sd * 4);
    }

    for (int lt = l0; lt < l1; lt += KS) {
        // ---- stage B (regs from last iteration / prologue) ----
#pragma unroll
        for (int it = 0; it < 8; ++it) {
            const int lrow = it * 8 + srow;
            unsigned* w = (unsigned*)&smB[lrow][sd * 4];
            w[0] = (unsigned)f2bf(ld[it].x) | ((unsigned)f2bf(ld[it].y) << 16);
            w[1] = (unsigned)f2bf(ld[it].z) | ((unsigned)f2bf(ld[it].w) << 16);
        }
        __syncthreads();                       // tile staged

        // ---- prefetch next tile's B globals (fly under MFMA phase) ----
        const int ltn = lt + KS;
        if (ltn < l1) {
#pragma unroll
            for (int it = 0; it < 8; ++it) {
                const int l = ltn + it * 8 + srow;
                ld[it] = make_float4(0.f, 0.f, 0.f, 0.f);
                if (l < l1)
                    ld[it] = *(const float4*)(vp_b + (size_t)l * D + sd * 4);
            }
        }

        // ---- A fragments: direct coalesced b128 loads from ws (L2/L3) ----
        const short8* mt = mws_b + ((size_t)(lt >> 6)) * 8 * 64;
        short8 af[2][4];
#pragma unroll
        for (int ks = 0; ks < 2; ++ks)
#pragma unroll
            for (int mf = 0; mf < 4; ++mf)
                af[ks][mf] = mt[(ks * 4 + mf) * 64 + lane];

        // ---- den accumulate (one load per tile, dcb==0 only) ----
        if (dcb == 0 && tid < VV)
            denacc += dt_b[(size_t)(lt >> 6) * VV + tid];

        // ---- MFMA: 2 k-halves x 4 m-frags x 2 n-frags ----
#pragma unroll
        for (int ks = 0; ks < 2; ++ks) {
#pragma unroll
            for (int nf = 0; nf < 2; ++nf) {
                const int colx  = wave * 32 + nf * 16 + fcol;
                const int kbase = ks * 32 + foct * 8;
                union { unsigned short h[8]; short8 s; } bf;
#pragma unroll
                for (int j = 0; j < 8; ++j)
                    bf.h[j] = smB[kbase + j][colx];
#pragma unroll
                for (int mf = 0; mf < 4; ++mf)
                    acc[mf][nf] = __builtin_amdgcn_mfma_f32_16x16x32_bf16(
                        af[ks][mf], bf.s, acc[mf][nf], 0, 0, 0);
            }
        }
        __syncthreads();                       // MFMA reads done; smB reusable
    }

    // ---- den partial ----
    if (dcb == 0 && tid < VV)
        den_part[((size_t)b * KCH + kblk) * VV + tid] = denacc;

    // ---- numerator partials (C/D: col=lane&15, row=(lane>>4)*4+r) ----
    float* basep = num_part + ((size_t)b * KCH + kblk) * VV * (size_t)D + d0 + wave * 32;
#pragma unroll
    for (int mf = 0; mf < 4; ++mf) {
#pragma unroll
        for (int nf = 0; nf < 2; ++nf) {
            const int colx = nf * 16 + fcol;
            const int row0 = mf * 16 + foct * 4;
#pragma unroll
            for (int r = 0; r < 4; ++r)
                basep[(size_t)(row0 + r) * D + colx] = acc[mf][nf][r];
        }
    }
}

// ---------------- reduce ----------------
__global__ __launch_bounds__(256)
void dvs_reduce(const float* __restrict__ num_part,
                const float* __restrict__ den_part,
                const int*   __restrict__ v_len,
                float*       __restrict__ out,
                int D, int total4)
{
    const int idx = blockIdx.x * 256 + threadIdx.x;
    if (idx >= total4) return;
    const int dq4 = D / 4;
    const int d4  = idx % dq4;
    const int bv  = idx / dq4;
    const int b   = bv / VV;
    const int v   = bv - b * VV;

    const int Lv    = v_len[b];
    const int chunk = (((Lv + KCH - 1) / KCH) + 63) & ~63;
    const int nk    = (Lv + chunk - 1) / chunk;      // valid chunk slots

    float  den = 1e-6f;
    float4 num = make_float4(0.f, 0.f, 0.f, 0.f);
    for (int k = 0; k < nk; ++k) {
        den += den_part[((size_t)b * KCH + k) * VV + v];
        const float4 p = ((const float4*)(num_part +
                          (((size_t)b * KCH + k) * VV + v) * (size_t)D))[d4];
        num.x += p.x; num.y += p.y; num.z += p.z; num.w += p.w;
    }
    const float inv = 1.0f / den;
    ((float4*)out)[(size_t)bv * dq4 + d4] =
        make_float4(num.x * inv, num.y * inv, num.z * inv, num.w * inv);
}

extern "C" void kernel_launch(void* const* d_in, const int* in_sizes, int n_in,
                              void* d_out, int out_size, void* d_ws, size_t ws_size,
                              hipStream_t stream)
{
    const float* v_pad     = (const float*)d_in[0];
    const int*   v_len     = (const int*)d_in[1];
    const int*   grid_thws = (const int*)d_in[2];
    const float* centers   = (const float*)d_in[3];
    float*       out       = (float*)d_out;

    const int B  = in_sizes[1];
    const int D  = out_size / (B * VV);
    const int L  = in_sizes[0] / (B * D);
    const int NT = (L + KS - 1) / KS;

    // workspace layout (all 16B-aligned)
    float*          num_part = (float*)d_ws;                               // B*KCH*V*D f32
    float*          den_part = num_part + (size_t)B * KCH * VV * D;        // B*KCH*V
    float*          den_tile = den_part + (size_t)B * KCH * VV;            // B*NT*V
    unsigned short* mws      = (unsigned short*)(den_tile + (size_t)B * NT * VV);

    dim3 gridP(NT, B);
    dvs_prep<<<gridP, 256, 0, stream>>>(v_len, grid_thws, centers, mws,
                                        den_tile, NT);

    dim3 gridG(KCH, D / DC, B);
    dvs_mfma<<<gridG, NTH, 0, stream>>>(v_pad, v_len, mws, den_tile,
                                        num_part, den_part, L, D, NT);

    const int total4 = B * VV * D / 4;
    dvs_reduce<<<(total4 + 255) / 256, 256, 0, stream>>>(num_part, den_part,
                                                         v_len, out, D, total4);
}